// Round 10
// baseline (81.205 us; speedup 1.0000x reference)
//
#include <hip/hip_runtime.h>
#include <hip/hip_bf16.h>
#include <stdint.h>

typedef __attribute__((ext_vector_type(4))) int   i32x4;
typedef __attribute__((ext_vector_type(8))) int   i32x8;
typedef __attribute__((ext_vector_type(4))) float f32x4;

#define MDIM   4096
#define NDIM   4096
#define KBYTES 2048   // K=4096 fp4 elems -> 2048 packed bytes per row
#define NKBLK  128    // K/32 scale blocks per row

#define BM   128
#define BN   128
#define BKB  64                  // K-bytes per tile (= 128 fp4 elems = 4 scale blocks)
#define KT   (KBYTES / BKB)      // 32 K-tiles

#define BARF()  asm volatile("s_barrier" ::: "memory")
#define LGKM0() asm volatile("s_waitcnt lgkmcnt(0)" ::: "memory")
// Counted drains (T4). Issue groups alternate: at even tile we issue
// {4 data + 2 scale} = 6 ops for kt+2; at odd tile {4 data}.
// Tile-end outstanding = [G(kt+1)][G(kt+2)]; wait = |G(kt+2)|.
#define VMC6()  asm volatile("s_waitcnt vmcnt(6)" ::: "memory")
#define VMC4()  asm volatile("s_waitcnt vmcnt(4)" ::: "memory")

// ---------------- repack: int32-per-byte -> packed bytes ----------------
__global__ void repack_bytes(const int* __restrict__ a, const int* __restrict__ b,
                             uint32_t* __restrict__ ap, uint32_t* __restrict__ bp) {
  const size_t n4 = (size_t)MDIM * KBYTES / 4;
  for (size_t i = (size_t)blockIdx.x * blockDim.x + threadIdx.x; i < n4;
       i += (size_t)gridDim.x * blockDim.x) {
    i32x4 va = *(const i32x4*)(a + i * 4);
    ap[i] = (uint32_t)(va.x & 255) | ((uint32_t)(va.y & 255) << 8) |
            ((uint32_t)(va.z & 255) << 16) | ((uint32_t)(va.w & 255) << 24);
    i32x4 vb = *(const i32x4*)(b + i * 4);
    bp[i] = (uint32_t)(vb.x & 255) | ((uint32_t)(vb.y & 255) << 8) |
            ((uint32_t)(vb.z & 255) << 16) | ((uint32_t)(vb.w & 255) << 24);
  }
}

// ---- scales: float -> uint8 E8M0, per-(tile-PAIR, 128-row-block) 1KB blocks ----
// Layout: [pair(16)][rowblk(32)][kb&7 (8)][m&15 (16)][(m>>4)&7 (8)] = 512 KB.
// One (pair, rowblk) block = 1 KB = one full-wave global_load_lds op.
__global__ void repack_scales(const float* __restrict__ sa, const float* __restrict__ sb,
                              uint8_t* __restrict__ satT, uint8_t* __restrict__ sbtT) {
  int t = blockIdx.x * blockDim.x + threadIdx.x;
  if (t >= MDIM * NKBLK) return;
  int m  = t >> 7;     // row
  int kb = t & 127;    // k-block
  int o  = ((kb >> 3) * 32 + (m >> 7)) * 1024 + (kb & 7) * 128 + (m & 15) * 8
           + ((m >> 4) & 7);
  satT[o] = (uint8_t)(int)sa[t];
  sbtT[o] = (uint8_t)(int)sb[t];
}

__device__ __forceinline__ i32x8 frag8(i32x4 v) {
  i32x8 r = {v.x, v.y, v.z, v.w, 0, 0, 0, 0};
  return r;
}

// ---- MXFP4 GEMM: 128x128 tile, 4 waves, 4 independent blocks/CU (TLP) ---------
// LDS/block: data [buf(2)][A|B][128 rows][64B] = 32768 B; scales [scb(2)][A1K|B1K]
// = 4096 B @ +32768. Total 36864 B -> 4 blocks/CU (R9 bug: allocated 34816,
// SCB(1) was out of bounds -> garbage E8M0 exponents -> absmax blowup).
__global__ __launch_bounds__(256, 4) void mxfp4_gemm(
    const uint8_t* __restrict__ ap, const uint8_t* __restrict__ bp,
    const uint8_t* __restrict__ satT, const uint8_t* __restrict__ sbtT,
    float* __restrict__ out) {
  extern __shared__ uint8_t lds[];

  const int tid  = threadIdx.x;
  const int lane = tid & 63;
  const int w    = tid >> 6;        // wave 0..3
  const int wrow = w >> 1;          // 2x2 wave grid, 64x64 out each
  const int wcol = w & 1;
  const int g    = lane >> 4;       // k-group 0..3 (32 fp4 elems = 1 scale block)
  const int l15  = lane & 15;

  // XCD-aware swizzle (nwg=1024, 1024%8==0 -> simple bijection); consecutive
  // wgid share an A-panel row (by) for L2 locality.
  const int wgid = (blockIdx.x & 7) * 128 + (blockIdx.x >> 3);
  const int bx = wgid & 31;
  const int by = wgid >> 5;

  const uint8_t* aBase = ap + (size_t)(by * BM) * KBYTES;
  const uint8_t* bBase = bp + (size_t)(bx * BN) * KBYTES;

  // R5 swizzle (HW-verified ~0 conflicts): LDS[row][d] holds global slot
  // d ^ ((row>>1)&3); frag read slot = g ^ ((l15>>1)&3).
  const int rdslot = (g ^ ((l15 >> 1) & 3)) * 16;
  const int soff   = (lane >> 2) * KBYTES + (((lane & 3) ^ ((lane >> 3) & 3)) * 16);
  const int arow0  = w * 32;        // each wave stages 32 A-rows + 32 B-rows

#define PLANE(bufi, mat) (lds + (bufi) * 16384 + (mat) * 8192)
#define SCB(i)           (lds + 32768 + (i) * 2048)

// 4 ops: 2 for A (2x16 rows x 64B), 2 for B
#define STAGE_DATA(bufi, ktX)                                                             \
  do {                                                                                    \
    const uint8_t* _sa = aBase + (size_t)arow0 * KBYTES + (ktX) * BKB + soff;             \
    const uint8_t* _sb = bBase + (size_t)arow0 * KBYTES + (ktX) * BKB + soff;             \
    uint8_t* _da = PLANE(bufi, 0) + arow0 * 64;                                           \
    uint8_t* _db = PLANE(bufi, 1) + arow0 * 64;                                           \
    __builtin_amdgcn_global_load_lds((__attribute__((address_space(1))) void*)_sa,        \
        (__attribute__((address_space(3))) void*)_da, 16, 0, 0);                          \
    __builtin_amdgcn_global_load_lds((__attribute__((address_space(1))) void*)(_sa + 16 * KBYTES), \
        (__attribute__((address_space(3))) void*)(_da + 1024), 16, 0, 0);                 \
    __builtin_amdgcn_global_load_lds((__attribute__((address_space(1))) void*)_sb,        \
        (__attribute__((address_space(3))) void*)(_db), 16, 0, 0);                        \
    __builtin_amdgcn_global_load_lds((__attribute__((address_space(1))) void*)(_sb + 16 * KBYTES), \
        (__attribute__((address_space(3))) void*)(_db + 1024), 16, 0, 0);                 \
  } while (0)

// 2 ops: A 1KB + B 1KB scale blocks for a tile-PAIR (redundant across 4 waves;
// keeps per-wave vmcnt accounting uniform)
#define STAGE_SCALES(sidx, pairX)                                                         \
  do {                                                                                    \
    const uint8_t* _ssa = satT + ((size_t)(pairX) * 32 + by) * 1024 + lane * 16;          \
    const uint8_t* _ssb = sbtT + ((size_t)(pairX) * 32 + bx) * 1024 + lane * 16;          \
    uint8_t* _dsc = SCB(sidx);                                                            \
    __builtin_amdgcn_global_load_lds((__attribute__((address_space(1))) void*)_ssa,       \
        (__attribute__((address_space(3))) void*)_dsc, 16, 0, 0);                         \
    __builtin_amdgcn_global_load_lds((__attribute__((address_space(1))) void*)_ssb,       \
        (__attribute__((address_space(3))) void*)(_dsc + 1024), 16, 0, 0);                \
  } while (0)

  f32x4 acc[4][4] = {};

// One K-tile: merged compute phase (reads + 16 MFMA, compiler-scheduled
// lgkmcnt), then LGKM0+BAR1, stage kt+2 into the just-freed buffer, counted
// drain of kt+1's group, BAR2.
#define TILE(ktv, DOSCALES, VMCW)                                                         \
  do {                                                                                    \
    const int _cur = (ktv) & 1;                                                           \
    const uint8_t* _A = PLANE(_cur, 0);                                                   \
    const uint8_t* _B = PLANE(_cur, 1);                                                   \
    const uint8_t* _scb = SCB(((ktv) >> 1) & 1);                                          \
    const uint32_t _sAk = *(const uint32_t*)(_scb + (((ktv) & 1) * 4 + g) * 128           \
                                             + l15 * 8 + wrow * 4);                       \
    const uint32_t _sBk = *(const uint32_t*)(_scb + 1024 + (((ktv) & 1) * 4 + g) * 128    \
                                             + l15 * 8 + wcol * 4);                       \
    i32x4 _af[4], _bf[4];                                                                 \
    _Pragma("unroll")                                                                     \
    for (int ns = 0; ns < 4; ++ns)                                                        \
      _bf[ns] = *(const i32x4*)(_B + (wcol * 64 + ns * 16 + l15) * 64 + rdslot);          \
    _Pragma("unroll")                                                                     \
    for (int ms = 0; ms < 4; ++ms)                                                        \
      _af[ms] = *(const i32x4*)(_A + (wrow * 64 + ms * 16 + l15) * 64 + rdslot);          \
    __builtin_amdgcn_s_setprio(1);                                                        \
    _Pragma("unroll")                                                                     \
    for (int ms = 0; ms < 4; ++ms) {                                                      \
      const int _sa = (int)((_sAk >> (ms * 8)) & 0xffu);                                  \
      _Pragma("unroll")                                                                   \
      for (int ns = 0; ns < 4; ++ns)                                                      \
        acc[ms][ns] = __builtin_amdgcn_mfma_scale_f32_16x16x128_f8f6f4(                   \
            frag8(_af[ms]), frag8(_bf[ns]), acc[ms][ns], 4, 4,                            \
            0, _sa, 0, (int)((_sBk >> (ns * 8)) & 0xffu));                                \
    }                                                                                     \
    __builtin_amdgcn_s_setprio(0);                                                        \
    LGKM0();                                                                              \
    BARF();                                                                               \
    const int _kt2 = ((ktv) + 2) & (KT - 1);                                              \
    STAGE_DATA(_cur, _kt2);                                                               \
    if (DOSCALES) STAGE_SCALES((((ktv) >> 1) + 1) & 1, (((ktv) + 2) >> 1) & 15);          \
    VMCW();                                                                               \
    BARF();                                                                               \
  } while (0)

  // ------- prologue: G0 = {kt0 data + pair0 scales} (6), G1 = {kt1 data} (4) -----
  STAGE_DATA(0, 0);
  STAGE_SCALES(0, 0);
  STAGE_DATA(1, 1);
  VMC4();     // drain G0 (tile 0 + its scales ready); G1 stays in flight
  BARF();

  for (int kt = 0; kt < KT; kt += 2) {
    TILE(kt, 1, VMC6);       // even: issues 6-op group for kt+2
    TILE(kt + 1, 0, VMC4);   // odd: issues 4-op group for kt+3
  }

  // epilogue: D mapping row=(lane>>4)*4+r, col=lane&15 per 16x16 block
  float* ob = out + (size_t)(by * BM + wrow * 64) * NDIM + bx * BN + wcol * 64;
#pragma unroll
  for (int ms = 0; ms < 4; ++ms)
#pragma unroll
    for (int ns = 0; ns < 4; ++ns) {
#pragma unroll
      for (int r = 0; r < 4; ++r)
        ob[(size_t)(ms * 16 + g * 4 + r) * NDIM + ns * 16 + l15] = acc[ms][ns][r];
    }
#undef TILE
#undef STAGE_DATA
#undef STAGE_SCALES
#undef PLANE
#undef SCB
}

extern "C" void kernel_launch(void* const* d_in, const int* in_sizes, int n_in,
                              void* d_out, int out_size, void* d_ws, size_t ws_size,
                              hipStream_t stream) {
  (void)in_sizes; (void)n_in; (void)out_size; (void)ws_size;
  const int*   a  = (const int*)d_in[0];
  const int*   b  = (const int*)d_in[1];
  const float* sa = (const float*)d_in[2];
  const float* sb = (const float*)d_in[3];
  float* out = (float*)d_out;

  uint8_t* ws = (uint8_t*)d_ws;
  uint32_t* ap = (uint32_t*)ws;                          // 8 MB packed A
  uint32_t* bp = (uint32_t*)(ws + (8u << 20));           // 8 MB packed B
  uint8_t*  satT = ws + (16u << 20);                     // 512 KB scales A (tiled)
  uint8_t*  sbtT = ws + (16u << 20) + (512u << 10);      // 512 KB scales B (tiled)

  repack_bytes<<<2048, 256, 0, stream>>>(a, b, ap, bp);
  repack_scales<<<(MDIM * NKBLK + 255) / 256, 256, 0, stream>>>(sa, sb, satT, sbtT);

  hipFuncSetAttribute((const void*)mxfp4_gemm,
                      hipFuncAttributeMaxDynamicSharedMemorySize, 36864);

  dim3 grid(32 * 32);   // 1024 blocks of 128x128; 4 resident/CU
  mxfp4_gemm<<<grid, 256, 36864, stream>>>((const uint8_t*)ap, (const uint8_t*)bp,
                                           satT, sbtT, out);
}

// Round 11
// 69.751 us; speedup vs baseline: 1.1642x; 1.1642x over previous
//
#include <hip/hip_runtime.h>
#include <hip/hip_bf16.h>
#include <stdint.h>

typedef __attribute__((ext_vector_type(4))) int          i32x4;
typedef __attribute__((ext_vector_type(8))) int          i32x8;
typedef __attribute__((ext_vector_type(4))) float        f32x4;
typedef __attribute__((ext_vector_type(4))) unsigned int u32x4;

#define MDIM   4096
#define NDIM   4096
#define KBYTES 2048   // K=4096 fp4 elems -> 2048 packed bytes per row
#define NKBLK  128    // K/32 scale blocks per row

#define BM   128
#define BN   128
#define BKB  128                 // K-bytes per step (= 256 fp4 elems = 8 scale blocks)
#define KT   (KBYTES / BKB)      // 16 K-steps

#define BARF()  asm volatile("s_barrier" ::: "memory")
#define LGKM0() asm volatile("s_waitcnt lgkmcnt(0)" ::: "memory")
#define VM0()   asm volatile("s_waitcnt vmcnt(0)" ::: "memory")

// ---- fused repack: bytes (u32x4 stores) + scales, one kernel -------------------
// grid = 524288 threads exactly: one u32x4 (16 packed bytes) per matrix per
// thread (MDIM*KBYTES/16 = 524288) and one scale entry per matrix per thread
// (MDIM*NKBLK = 524288).
// Scale layout (R10-proven): [kt(16)][rowblk(32)][kb&7(8)][m&15(16)][(m>>4)&7(8)]
// = 512 KB; one (kt,rowblk) block = 1 KB.
__global__ void repack_all(const int* __restrict__ a, const int* __restrict__ b,
                           const float* __restrict__ sa, const float* __restrict__ sb,
                           u32x4* __restrict__ ap, u32x4* __restrict__ bp,
                           uint8_t* __restrict__ satT, uint8_t* __restrict__ sbtT) {
  const int t = blockIdx.x * blockDim.x + threadIdx.x;
  {
    const size_t i = (size_t)t;
    uint32_t r[4], s[4];
#pragma unroll
    for (int q = 0; q < 4; ++q) {
      i32x4 va = *(const i32x4*)(a + i * 16 + q * 4);
      r[q] = (uint32_t)(va.x & 255) | ((uint32_t)(va.y & 255) << 8) |
             ((uint32_t)(va.z & 255) << 16) | ((uint32_t)(va.w & 255) << 24);
      i32x4 vb = *(const i32x4*)(b + i * 16 + q * 4);
      s[q] = (uint32_t)(vb.x & 255) | ((uint32_t)(vb.y & 255) << 8) |
             ((uint32_t)(vb.z & 255) << 16) | ((uint32_t)(vb.w & 255) << 24);
    }
    u32x4 rv = {r[0], r[1], r[2], r[3]};
    u32x4 sv = {s[0], s[1], s[2], s[3]};
    ap[i] = rv;
    bp[i] = sv;
  }
  {
    const int m = t >> 7, kb = t & 127;
    const int o = ((kb >> 3) * 32 + (m >> 7)) * 1024 + (kb & 7) * 128 + (m & 15) * 8
                  + ((m >> 4) & 7);
    satT[o] = (uint8_t)(int)sa[t];
    sbtT[o] = (uint8_t)(int)sb[t];
  }
}

__device__ __forceinline__ i32x8 frag8(i32x4 v) {
  i32x8 r = {v.x, v.y, v.z, v.w, 0, 0, 0, 0};
  return r;
}

// ---- MXFP4 GEMM: m97/m153-replica. 128x128 tile, BK=128B, SINGLE buffer, ------
// ---- 2 barriers/step, 32 MFMA/step/wave, 4 blocks/CU, LDS-staged scales. ------
// LDS: A[128][128B] + B[128][128B] = 32 KB; scales A 1KB + B 1KB @ +32768.
// Total 34816 B (static) -> 4 blocks/CU.
__global__ __launch_bounds__(256, 4) void mxfp4_gemm(
    const uint8_t* __restrict__ ap, const uint8_t* __restrict__ bp,
    const uint8_t* __restrict__ satT, const uint8_t* __restrict__ sbtT,
    float* __restrict__ out) {
  __shared__ __align__(16) uint8_t lds[34816];

  const int tid  = threadIdx.x;
  const int lane = tid & 63;
  const int w    = tid >> 6;        // wave 0..3
  const int wrow = w >> 1;          // 2x2 wave grid, 64x64 out each
  const int wcol = w & 1;
  const int g    = lane >> 4;       // k-group 0..3 (one scale block each)
  const int l15  = lane & 15;
  const int lx   = lane & 7;        // read-side xor (== frag row & 7)

  // XCD-aware bijective swizzle (nwg=1024, %8==0)
  const int wgid = (blockIdx.x & 7) * 128 + (blockIdx.x >> 3);
  const int bx = wgid & 31;
  const int by = wgid >> 5;

  const uint8_t* aBase = ap + (size_t)(by * BM) * KBYTES;
  const uint8_t* bBase = bp + (size_t)(bx * BN) * KBYTES;
  uint8_t* const lA  = lds;
  uint8_t* const lB  = lds + 16384;
  uint8_t* const scb = lds + 32768;

  // R1-proven zero-conflict swizzle: LDS[row][d] holds global slot d^(row&7);
  // read slot for (kw,g) = (kw*4+g) ^ (row&7).
  const int srow  = lane >> 3;              // 0..7 within an 8-row chunk
  const int sslot = (lane & 7) ^ srow;      // involution, pre-swizzled source
  const int soff  = srow * KBYTES + sslot * 16;
  const int arow0 = w * 32;                 // each wave stages 32 A + 32 B rows

// 8 data ops (4 chunks x 1KB for A, same for B) + 2 scale ops = 10 vmem/wave/step
#define STAGE(ktX)                                                                        \
  do {                                                                                    \
    _Pragma("unroll")                                                                     \
    for (int c = 0; c < 4; ++c) {                                                         \
      const int r0 = arow0 + c * 8;                                                       \
      __builtin_amdgcn_global_load_lds(                                                   \
          (__attribute__((address_space(1))) void*)(aBase + (size_t)r0 * KBYTES + (ktX) * BKB + soff), \
          (__attribute__((address_space(3))) void*)(lA + r0 * 128), 16, 0, 0);            \
      __builtin_amdgcn_global_load_lds(                                                   \
          (__attribute__((address_space(1))) void*)(bBase + (size_t)r0 * KBYTES + (ktX) * BKB + soff), \
          (__attribute__((address_space(3))) void*)(lB + r0 * 128), 16, 0, 0);            \
    }                                                                                     \
    __builtin_amdgcn_global_load_lds(                                                     \
        (__attribute__((address_space(1))) void*)(satT + ((size_t)(ktX) * 32 + by) * 1024 + lane * 16), \
        (__attribute__((address_space(3))) void*)(scb + lane * 16), 16, 0, 0);            \
    __builtin_amdgcn_global_load_lds(                                                     \
        (__attribute__((address_space(1))) void*)(sbtT + ((size_t)(ktX) * 32 + bx) * 1024 + lane * 16), \
        (__attribute__((address_space(3))) void*)(scb + 1024 + lane * 16), 16, 0, 0);     \
  } while (0)

  f32x4 acc[4][4] = {};
  i32x4 af[4], bf[4];

  STAGE(0);

  for (int kt = 0; kt < KT; ++kt) {
    VM0();     // own 10 staging ops landed; barrier => all waves' landed
    BARF();

    // current tile's scales (one dword per operand per kw-half)
    const uint32_t sAk0 = *(const uint32_t*)(scb + (0 + g) * 128 + l15 * 8 + wrow * 4);
    const uint32_t sAk1 = *(const uint32_t*)(scb + (4 + g) * 128 + l15 * 8 + wrow * 4);
    const uint32_t sBk0 = *(const uint32_t*)(scb + 1024 + (0 + g) * 128 + l15 * 8 + wcol * 4);
    const uint32_t sBk1 = *(const uint32_t*)(scb + 1024 + (4 + g) * 128 + l15 * 8 + wcol * 4);

    // ---- kw0: K elems 0..127 of this step ----
    {
      const int slotx = ((0 + g) ^ lx) * 16;
#pragma unroll
      for (int ns = 0; ns < 4; ++ns)
        bf[ns] = *(const i32x4*)(lB + (wcol * 64 + ns * 16 + l15) * 128 + slotx);
#pragma unroll
      for (int ms = 0; ms < 4; ++ms)
        af[ms] = *(const i32x4*)(lA + (wrow * 64 + ms * 16 + l15) * 128 + slotx);
      __builtin_amdgcn_s_setprio(1);
#pragma unroll
      for (int ms = 0; ms < 4; ++ms) {
        const int sa = (int)((sAk0 >> (ms * 8)) & 0xffu);
#pragma unroll
        for (int ns = 0; ns < 4; ++ns)
          acc[ms][ns] = __builtin_amdgcn_mfma_scale_f32_16x16x128_f8f6f4(
              frag8(af[ms]), frag8(bf[ns]), acc[ms][ns], 4, 4,
              0, sa, 0, (int)((sBk0 >> (ns * 8)) & 0xffu));
      }
      __builtin_amdgcn_s_setprio(0);
    }
    // ---- kw1: K elems 128..255 (reuses af/bf regs; compiler pipelines) ----
    {
      const int slotx = ((4 + g) ^ lx) * 16;
#pragma unroll
      for (int ns = 0; ns < 4; ++ns)
        bf[ns] = *(const i32x4*)(lB + (wcol * 64 + ns * 16 + l15) * 128 + slotx);
#pragma unroll
      for (int ms = 0; ms < 4; ++ms)
        af[ms] = *(const i32x4*)(lA + (wrow * 64 + ms * 16 + l15) * 128 + slotx);
      __builtin_amdgcn_s_setprio(1);
#pragma unroll
      for (int ms = 0; ms < 4; ++ms) {
        const int sa = (int)((sAk1 >> (ms * 8)) & 0xffu);
#pragma unroll
        for (int ns = 0; ns < 4; ++ns)
          acc[ms][ns] = __builtin_amdgcn_mfma_scale_f32_16x16x128_f8f6f4(
              frag8(af[ms]), frag8(bf[ns]), acc[ms][ns], 4, 4,
              0, sa, 0, (int)((sBk1 >> (ns * 8)) & 0xffu));
      }
      __builtin_amdgcn_s_setprio(0);
    }

    LGKM0();   // all reads (frags + scale dwords) complete -> buffer free
    BARF();
    if (kt + 1 < KT) STAGE(kt + 1);   // refill single buffer for next step
  }

  // epilogue: D mapping row=(lane>>4)*4+r, col=lane&15 per 16x16 block
  float* ob = out + (size_t)(by * BM + wrow * 64) * NDIM + bx * BN + wcol * 64;
#pragma unroll
  for (int ms = 0; ms < 4; ++ms)
#pragma unroll
    for (int ns = 0; ns < 4; ++ns) {
#pragma unroll
      for (int r = 0; r < 4; ++r)
        ob[(size_t)(ms * 16 + g * 4 + r) * NDIM + ns * 16 + l15] = acc[ms][ns][r];
    }
#undef STAGE
}

extern "C" void kernel_launch(void* const* d_in, const int* in_sizes, int n_in,
                              void* d_out, int out_size, void* d_ws, size_t ws_size,
                              hipStream_t stream) {
  (void)in_sizes; (void)n_in; (void)out_size; (void)ws_size;
  const int*   a  = (const int*)d_in[0];
  const int*   b  = (const int*)d_in[1];
  const float* sa = (const float*)d_in[2];
  const float* sb = (const float*)d_in[3];
  float* out = (float*)d_out;

  uint8_t* ws = (uint8_t*)d_ws;
  u32x4*   ap   = (u32x4*)ws;                            // 8 MB packed A
  u32x4*   bp   = (u32x4*)(ws + (8u << 20));             // 8 MB packed B
  uint8_t* satT = ws + (16u << 20);                      // 512 KB scales A (tiled)
  uint8_t* sbtT = ws + (16u << 20) + (512u << 10);       // 512 KB scales B (tiled)

  repack_all<<<2048, 256, 0, stream>>>(a, b, sa, sb, ap, bp, satT, sbtT);

  dim3 grid(32 * 32);   // 1024 blocks of 128x128; 4 resident/CU
  mxfp4_gemm<<<grid, 256, 0, stream>>>((const uint8_t*)ap, (const uint8_t*)bp,
                                       satT, sbtT, out);
}